// Round 27
// baseline (151.264 us; speedup 1.0000x reference)
//
#include <hip/hip_runtime.h>
#include <cstdint>

typedef unsigned short u16;
typedef unsigned int u32;
typedef short bf16x8 __attribute__((ext_vector_type(8)));
typedef float f32x4 __attribute__((ext_vector_type(4)));

__device__ __forceinline__ u16 f2bf(float f) {
  unsigned u = __builtin_bit_cast(unsigned, f);
  u = (u + 0x7fffu + ((u >> 16) & 1u)) >> 16;
  return (u16)u;
}
// truncating pack (P-tile only: P>=0, bounded 2^8; 1 op vs 4, err <= 2^-8 rel)
__device__ __forceinline__ u16 f2bf_t(float f) {
  return (u16)(__builtin_bit_cast(unsigned, f) >> 16);
}

// async global->LDS, 16B per lane. LDS dst = wave-uniform base (HW adds lane*16);
// global src is per-lane.
__device__ __forceinline__ void gload_lds16(const void* g, void* l) {
  __builtin_amdgcn_global_load_lds(
      (const __attribute__((address_space(1))) unsigned int*)g,
      (__attribute__((address_space(3))) unsigned int*)l, 16, 0, 0);
}

// ---------------- Kernel 0: fp32 -> bf16 elementwise ------------------------
__global__ void cvt_f32_bf16(const float* __restrict__ src, u16* __restrict__ dst, int n4) {
  int i = blockIdx.x * 256 + threadIdx.x;
  if (i < n4) {
    float4 v = *reinterpret_cast<const float4*>(src + (size_t)i * 4);
    u16* d = dst + (size_t)i * 4;
    d[0] = f2bf(v.x); d[1] = f2bf(v.y); d[2] = f2bf(v.z); d[3] = f2bf(v.w);
  }
}

// ---------------- Kernel 1: weight transpose (fp32 in, bf16 out) ------------
__global__ void transpose_w_kernel(const float* __restrict__ Wq, const float* __restrict__ Wk,
                                   const float* __restrict__ Wv, u16* __restrict__ Wt) {
  __shared__ u16 tile[64][72];
  const int bid = blockIdx.x;
  const int et = bid & 15;
  const int h  = (bid >> 4) & 15;
  const int p  = bid >> 8;
  const float* W = (p == 0) ? Wq : ((p == 1) ? Wk : Wv);
  const int tid = threadIdx.x;
  for (int idx = tid; idx < 4096; idx += 256) {
    int i = idx >> 6, d = idx & 63;
    tile[d][i] = f2bf(W[(size_t)(h * 1024 + et * 64 + i) * 64 + d]);
  }
  __syncthreads();
  for (int idx = tid; idx < 4096; idx += 256) {
    int dd = idx >> 6, i = idx & 63;
    Wt[(size_t)(p * 1024 + h * 64 + dd) * 1024 + et * 64 + i] = tile[dd][i];
  }
}

// ---------------- Kernel 2/4: GEMM v12 (r23 state, unchanged) ----------------
template <int N, int MODE>
__global__ __launch_bounds__(512, 1)
void gemm_bt2(const u16* __restrict__ A, const u16* __restrict__ Bt,
              u16* __restrict__ O0, u16* __restrict__ O1, u16* __restrict__ O2,
              float* __restrict__ Of, const float* __restrict__ bias) {
  constexpr int K = 1024, BK = 64, NT = K / BK;
  constexpr int nbn = N / 128;
  constexpr int nwg = 32 * nbn;
  constexpr int ABYTES = 256 * BK * 2;             // 32KB
  constexpr int BUFBYTES = ABYTES + 128 * BK * 2;  // 48KB
  __shared__ char SM[3][BUFBYTES];                 // 144KB ring; reused by epilogue
  const int tid = threadIdx.x;
  const int lane = tid & 63;
  const int wid = tid >> 6;
  const int bid = (blockIdx.x & 7) * (nwg / 8) + (blockIdx.x >> 3);
  const int m0 = (bid / nbn) * 256, n0 = (bid % nbn) * 128;
  const int wm = (wid >> 1) * 64, wn = (wid & 1) * 64;
  const int fr = lane & 15;
  const int fgb = (lane >> 4) << 4;
  const int swz = (fr & 7) << 4;

  f32x4 acc[4][4];
#pragma unroll
  for (int i = 0; i < 4; ++i)
#pragma unroll
    for (int j = 0; j < 4; ++j) acc[i][j] = f32x4{0.f, 0.f, 0.f, 0.f};

  auto stage = [&](char* base, int k0) {
#pragma unroll
    for (int i = 0; i < 4; ++i) {
      int cbase = i * 512 + wid * 64;
      int chunk = cbase + lane;
      int row = chunk >> 3;
      int cole = ((chunk & 7) ^ (row & 7)) << 3;
      gload_lds16(A + (size_t)(m0 + row) * K + k0 + cole, base + cbase * 16);
    }
#pragma unroll
    for (int i = 0; i < 2; ++i) {
      int cbase = i * 512 + wid * 64;
      int chunk = cbase + lane;
      int row = chunk >> 3;
      int cole = ((chunk & 7) ^ (row & 7)) << 3;
      gload_lds16(Bt + (size_t)(n0 + row) * K + k0 + cole, base + ABYTES + cbase * 16);
    }
  };

  stage(&SM[0][0], 0);
  stage(&SM[1][0], BK);
  asm volatile("s_waitcnt vmcnt(6)" ::: "memory");
  __builtin_amdgcn_s_barrier();
  __builtin_amdgcn_sched_barrier(0);

  int bc = 0;
  for (int t = 0; t < NT; ++t) {
    char* Ab = &SM[0][0] + bc * BUFBYTES;
    char* Bb = Ab + ABYTES;
    bf16x8 af[2][4], bf[2][4];
#pragma unroll
    for (int kk = 0; kk < 2; ++kk) {
      const int colb = (kk * 64 + fgb) ^ swz;
#pragma unroll
      for (int mi = 0; mi < 4; ++mi)
        af[kk][mi] = *reinterpret_cast<const bf16x8*>(Ab + (wm + mi * 16 + fr) * 128 + colb);
#pragma unroll
      for (int ni = 0; ni < 4; ++ni)
        bf[kk][ni] = *reinterpret_cast<const bf16x8*>(Bb + (wn + ni * 16 + fr) * 128 + colb);
    }
    if (t + 2 < NT) {
      int bn = bc + 2; if (bn >= 3) bn -= 3;
      stage(&SM[0][0] + bn * BUFBYTES, (t + 2) * BK);
    }
    __builtin_amdgcn_s_setprio(1);
#pragma unroll
    for (int kk = 0; kk < 2; ++kk)
#pragma unroll
      for (int mi = 0; mi < 4; ++mi)
#pragma unroll
        for (int ni = 0; ni < 4; ++ni)
          acc[mi][ni] = __builtin_amdgcn_mfma_f32_16x16x32_bf16(af[kk][mi], bf[kk][ni], acc[mi][ni], 0, 0, 0);
    __builtin_amdgcn_s_setprio(0);
    __builtin_amdgcn_sched_barrier(0);
    if (t + 2 < NT)
      asm volatile("s_waitcnt vmcnt(6)" ::: "memory");
    else if (t + 1 < NT)
      asm volatile("s_waitcnt vmcnt(0)" ::: "memory");
    __builtin_amdgcn_s_barrier();
    __builtin_amdgcn_sched_barrier(0);
    ++bc; if (bc == 3) bc = 0;
  }

  const int rq = (lane >> 4) << 2;  // C/D: col = lane&15, row = (lane>>4)*4 + reg
  if constexpr (MODE == 0) {
    const int pr = n0 >> 10;             // uniform per block
    const int hh0 = (n0 >> 6) & 15;      // first of 2 heads in this block
    if (pr < 2) {
      u16* T = (u16*)&SM[0][0];
#pragma unroll
      for (int ni = 0; ni < 4; ++ni)
#pragma unroll
        for (int mi = 0; mi < 4; ++mi)
#pragma unroll
          for (int r = 0; r < 4; ++r)
            T[(wm + mi * 16 + rq + r) * 132 + wn + ni * 16 + fr] = f2bf(acc[mi][ni][r]);
      __builtin_amdgcn_s_barrier();
      u16* O = (pr == 0) ? O0 : O1;      // [B,H,1024,64]
#pragma unroll
      for (int k = 0; k < 8; ++k) {
        int ch = tid + k * 512;
        int c16 = ch & 7;
        int hhh = (ch >> 3) & 1;
        int m = ch >> 4;
        int mg = m0 + m;
        int b = mg >> 10, t = mg & 1023;
        const u16* src = &T[m * 132 + hhh * 64 + c16 * 8];
        uint2 lo = *(const uint2*)(src);
        uint2 hi = *(const uint2*)(src + 4);
        uint4 val = {lo.x, lo.y, hi.x, hi.y};
        *(uint4*)(O + ((size_t)(b * 16 + hh0 + hhh) * 1024 + t) * 64 + c16 * 8) = val;
      }
    } else {
      u16* T2 = (u16*)&SM[0][0];         // [n=128][m=260]
#pragma unroll
      for (int ni = 0; ni < 4; ++ni)
#pragma unroll
        for (int mi = 0; mi < 4; ++mi) {
          u16 tmp[4];
#pragma unroll
          for (int r = 0; r < 4; ++r) tmp[r] = f2bf(acc[mi][ni][r]);
          *(uint2*)&T2[(wn + ni * 16 + fr) * 260 + wm + mi * 16 + rq] = *(const uint2*)tmp;
        }
      __builtin_amdgcn_s_barrier();
      const int b = m0 >> 10, tb = m0 & 1023;
#pragma unroll
      for (int k = 0; k < 8; ++k) {
        int ch = tid + k * 512;
        int mc = ch & 31;
        int dd2 = ch >> 5;
        const u16* src = &T2[dd2 * 260 + mc * 8];
        uint2 lo = *(const uint2*)(src);
        uint2 hi = *(const uint2*)(src + 4);
        uint4 val = {lo.x, lo.y, hi.x, hi.y};
        int hhh = dd2 >> 6, dd = dd2 & 63;
        *(uint4*)(O2 + ((size_t)(b * 16 + hh0 + hhh) * 64 + dd) * 1024 + tb + mc * 8) = val;
      }
    }
  } else {
    float* Tf = (float*)&SM[0][0];       // 256*132*4 = 135KB
#pragma unroll
    for (int ni = 0; ni < 4; ++ni) {
      int n = n0 + wn + ni * 16 + fr;
      float bv = bias[n];
#pragma unroll
      for (int mi = 0; mi < 4; ++mi)
#pragma unroll
        for (int r = 0; r < 4; ++r)
          Tf[(wm + mi * 16 + rq + r) * 132 + wn + ni * 16 + fr] = acc[mi][ni][r] + bv;
    }
    __builtin_amdgcn_s_barrier();
#pragma unroll
    for (int k = 0; k < 16; ++k) {
      int ch = tid + k * 512;
      int mc = ch & 31;
      int m = ch >> 5;
      float4 val = *(const float4*)&Tf[m * 132 + mc * 4];
      *(float4*)(Of + (size_t)(m0 + m) * N + n0 + mc * 4) = val;
    }
  }
}

// ---------------- Kernel 3: causal flash attention (v17) ---------------------
// v15 per-wave body, BLOCK DOUBLED: 512 threads / 8 waves / 256 q-rows per
// block -> each staged K/V tile + barrier amortized over 2x the q-rows, and
// stage cost per thread halves (1 K + 1 V gload).  LDS = K/V dbuf 32KB + P
// 8x2KB = 64KB -> 2 blocks/CU -> 16 waves/CU (vs 12 at the (256,3) ceiling).
// (512,1) leaves the 256-VGPR tier (per-wave live state ~84, r8/r23
// precedent) -- the only safe residency raise per the empirical cap law
// ((256,4)->64 cap spilled 3x).  Grid 512 = all co-resident.
__global__ __launch_bounds__(512, 1)
void attn_fwd(const u16* __restrict__ Q, const u16* __restrict__ K,
              const u16* __restrict__ V, u16* __restrict__ O) {
  __shared__ u16 Ksm[2][4096];   // [buf][64 t-rows x 64 d-cols], col-swizzled
  __shared__ u16 Vsm[2][4096];   // [buf][64 d-rows x 64 t-cols], col-swizzled
  __shared__ u16 Pl[8][2048];    // per-wave P (2 frags x 16x64), XOR-swizzled
  const int tid = threadIdx.x, lane = tid & 63, w = tid >> 6;  // w in 0..7
  const int bid = blockIdx.x;
  const int bh = bid & 127;          // low bits -> XCD affinity per head
  const int c  = 3 - (bid >> 7);     // descending work order, c in 0..3
  const int b = bh >> 4, h = bh & 15;
  const int q0w = c * 256 + w * 32;
  const int fr = lane & 15, fg = lane >> 4, fk = fg << 3;
  const int swz = (fr & 7) << 4;
  const int fgb = fg << 4;
  const u16* Qb = Q + (size_t)bh * 65536;
  const u16* Kb = K + (size_t)bh * 65536;
  const u16* Vb = V + (size_t)bh * 65536;
  char* Pw = (char*)&Pl[w][0];
  const float cst = 0.125f * 1.44269504088896f;   // hs^-0.5 * log2(e)
  const float THRraw = 8.0f / (0.125f * 1.44269504088896f);

  // 512 threads stage one 64x64 K tile + one 64x64 V^T tile: 1 chunk each.
  auto stage = [&](int buf, int st2) {
    const u16* Kt = Kb + st2 * 4096;
    const u16* Vt = Vb + st2 * 64;
    int cbase = w * 64;                        // wave-uniform chunk base
    int chunk = cbase + lane;                  // = tid, 512 chunks of 16B
    int row = chunk >> 3;
    int cole = ((chunk & 7) ^ (row & 7)) << 3;
    gload_lds16(Kt + row * 64 + cole, (char*)&Ksm[buf][0] + cbase * 16);
    gload_lds16(Vt + (size_t)row * 1024 + cole, (char*)&Vsm[buf][0] + cbase * 16);
  };

  bf16x8 qf[2][2];
#pragma unroll
  for (int qm = 0; qm < 2; ++qm)
#pragma unroll
    for (int kk = 0; kk < 2; ++kk)
      qf[qm][kk] = *reinterpret_cast<const bf16x8*>(&Qb[(q0w + qm * 16 + fr) * 64 + kk * 32 + fk]);

  f32x4 o[2][4];
  float mraw[2][4], negm[2][4], lrow[2][4];
#pragma unroll
  for (int qm = 0; qm < 2; ++qm)
#pragma unroll
    for (int i = 0; i < 4; ++i) {
      o[qm][i] = f32x4{0.f, 0.f, 0.f, 0.f};
      mraw[qm][i] = -1e30f; negm[qm][i] = 1e30f * cst; lrow[qm][i] = 0.f;
    }

  const int stmaxb = 4 * c + 3;   // block-uniform bound (top wave's limit)

  stage(0, 0);
  __syncthreads();
  int cur = 0;
  for (int st = 0; st <= stmaxb; ++st) {
    if (st < stmaxb) stage(cur ^ 1, st + 1);

    const bool active = (st * 64 <= q0w + 31);  // wave-uniform
    if (active) {
      f32x4 s[2][4];
#pragma unroll
      for (int qm = 0; qm < 2; ++qm)
#pragma unroll
        for (int i = 0; i < 4; ++i) s[qm][i] = f32x4{0.f, 0.f, 0.f, 0.f};
#pragma unroll
      for (int kk = 0; kk < 2; ++kk) {
        const int colb = (kk * 64 + fgb) ^ swz;
#pragma unroll
        for (int nf = 0; nf < 4; ++nf) {
          bf16x8 kf = *reinterpret_cast<const bf16x8*>(
              (const char*)&Ksm[cur][0] + (nf * 16 + fr) * 128 + colb);
          s[0][nf] = __builtin_amdgcn_mfma_f32_16x16x32_bf16(qf[0][kk], kf, s[0][nf], 0, 0, 0);
          s[1][nf] = __builtin_amdgcn_mfma_f32_16x16x32_bf16(qf[1][kk], kf, s[1][nf], 0, 0, 0);
        }
      }

#pragma unroll
      for (int qm = 0; qm < 2; ++qm) {
        const int qb = q0w + qm * 16;
        const bool need_mask = (st * 64 + 63 > qb);
        float sv[4][4];
#pragma unroll
        for (int nf = 0; nf < 4; ++nf)
#pragma unroll
          for (int r = 0; r < 4; ++r) {
            float xv = s[qm][nf][r];
            if (need_mask) {
              int sc = st * 64 + nf * 16 + fr;
              int qr = qb + fg * 4 + r;
              if (sc > qr) xv = -1e30f;
            }
            sv[nf][r] = xv;
          }
        float pmax[4];
#pragma unroll
        for (int r = 0; r < 4; ++r)
          pmax[r] = fmaxf(fmaxf(sv[0][r], sv[1][r]), fmaxf(sv[2][r], sv[3][r]));
        bool grew = (pmax[0] > mraw[qm][0] + THRraw) || (pmax[1] > mraw[qm][1] + THRraw) ||
                    (pmax[2] > mraw[qm][2] + THRraw) || (pmax[3] > mraw[qm][3] + THRraw);
        if (__any(grew)) {
#pragma unroll
          for (int r = 0; r < 4; ++r) {
            float m = pmax[r];
            m = fmaxf(m, __shfl_xor(m, 1));
            m = fmaxf(m, __shfl_xor(m, 2));
            m = fmaxf(m, __shfl_xor(m, 4));
            m = fmaxf(m, __shfl_xor(m, 8));
            float mnew = fmaxf(mraw[qm][r], m);
            float a = exp2f((mraw[qm][r] - mnew) * cst);
            lrow[qm][r] *= a;
            o[qm][0][r] *= a; o[qm][1][r] *= a; o[qm][2][r] *= a; o[qm][3][r] *= a;
            mraw[qm][r] = mnew;
            negm[qm][r] = -mnew * cst;
          }
        }
        char* Pq = Pw + qm * 2048;
#pragma unroll
        for (int r = 0; r < 4; ++r) {
          float sum = 0.f;
#pragma unroll
          for (int nf = 0; nf < 4; ++nf) {
            float pv = exp2f(fmaf(sv[nf][r], cst, negm[qm][r]));
            sum += pv;
            int mm = fg * 4 + r, nn = nf * 16 + fr;
            int byteoff = (mm * 128 + nn * 2) ^ ((mm & 7) << 4);
            *(u16*)(Pq + byteoff) = f2bf_t(pv);   // truncating pack (P only)
          }
          lrow[qm][r] += sum;
        }
      }

#pragma unroll
      for (int kk = 0; kk < 2; ++kk) {
        int rb = (fr * 128 + kk * 64 + fg * 16) ^ ((fr & 7) << 4);
        bf16x8 pa0 = *reinterpret_cast<const bf16x8*>(Pw + rb);
        bf16x8 pa1 = *reinterpret_cast<const bf16x8*>(Pw + 2048 + rb);
        const int colb = (kk * 64 + fgb) ^ swz;
#pragma unroll
        for (int df = 0; df < 4; ++df) {
          bf16x8 vfv = *reinterpret_cast<const bf16x8*>(
              (const char*)&Vsm[cur][0] + (df * 16 + fr) * 128 + colb);
          o[0][df] = __builtin_amdgcn_mfma_f32_16x16x32_bf16(pa0, vfv, o[0][df], 0, 0, 0);
          o[1][df] = __builtin_amdgcn_mfma_f32_16x16x32_bf16(pa1, vfv, o[1][df], 0, 0, 0);
        }
      }
    }

    __syncthreads();
    cur ^= 1;
  }

#pragma unroll
  for (int qm = 0; qm < 2; ++qm)
#pragma unroll
    for (int r = 0; r < 4; ++r) {
      float sum = lrow[qm][r];
      sum += __shfl_xor(sum, 1);
      sum += __shfl_xor(sum, 2);
      sum += __shfl_xor(sum, 4);
      sum += __shfl_xor(sum, 8);
      float inv = 1.0f / sum;
      int t = q0w + qm * 16 + fg * 4 + r;
      size_t base = ((size_t)b * 1024 + t) * 1024 + h * 64;
#pragma unroll
      for (int df = 0; df < 4; ++df) O[base + df * 16 + fr] = f2bf(o[qm][df][r] * inv);
    }
}

// ---------------- launcher ---------------------------------------------------
extern "C" void kernel_launch(void* const* d_in, const int* in_sizes, int n_in,
                              void* d_out, int out_size, void* d_ws, size_t ws_size,
                              hipStream_t stream) {
  (void)in_sizes; (void)n_in; (void)out_size; (void)ws_size;
  const float* x  = (const float*)d_in[0];
  const float* Wq = (const float*)d_in[1];
  const float* Wk = (const float*)d_in[2];
  const float* Wv = (const float*)d_in[3];
  const float* Wp = (const float*)d_in[4];
  const float* bp = (const float*)d_in[5];
  float* out = (float*)d_out;

  char* ws = (char*)d_ws;
  u16* xb  = (u16*)(ws);              // 16MB, reused as Ob after attn input dead
  u16* Ob  = (u16*)(ws);
  u16* Wt  = (u16*)(ws + 16777216);   // 6MB, reused as Wpb
  u16* Wpb = (u16*)(ws + 16777216);
  u16* Qb  = (u16*)(ws + 23068672);   // 16 MB: [B,H,1024,64]
  u16* Kb  = (u16*)(ws + 39845888);   // 16 MB
  u16* Vt  = (u16*)(ws + 56623104);   // 16 MB: [B,H,64,1024]

  cvt_f32_bf16<<<8192, 256, 0, stream>>>(x, xb, 2097152);
  transpose_w_kernel<<<768, 256, 0, stream>>>(Wq, Wk, Wv, Wt);
  gemm_bt2<3072, 0><<<768, 512, 0, stream>>>(xb, Wt, Qb, Kb, Vt, nullptr, nullptr);
  cvt_f32_bf16<<<1024, 256, 0, stream>>>(Wp, Wpb, 262144);
  attn_fwd<<<512, 512, 0, stream>>>(Qb, Kb, Vt, Ob);
  gemm_bt2<1024, 1><<<256, 512, 0, stream>>>(Ob, Wpb, nullptr, nullptr, nullptr, out, bp);
}

// Round 28
// 141.916 us; speedup vs baseline: 1.0659x; 1.0659x over previous
//
#include <hip/hip_runtime.h>
#include <cstdint>

typedef unsigned short u16;
typedef unsigned int u32;
typedef short bf16x8 __attribute__((ext_vector_type(8)));
typedef float f32x4 __attribute__((ext_vector_type(4)));

__device__ __forceinline__ u16 f2bf(float f) {
  unsigned u = __builtin_bit_cast(unsigned, f);
  u = (u + 0x7fffu + ((u >> 16) & 1u)) >> 16;
  return (u16)u;
}
// truncating pack (P-tile only: P>=0, bounded 2^8; 1 op vs 4, err <= 2^-8 rel)
__device__ __forceinline__ u16 f2bf_t(float f) {
  return (u16)(__builtin_bit_cast(unsigned, f) >> 16);
}

// async global->LDS, 16B per lane. LDS dst = wave-uniform base (HW adds lane*16);
// global src is per-lane.
__device__ __forceinline__ void gload_lds16(const void* g, void* l) {
  __builtin_amdgcn_global_load_lds(
      (const __attribute__((address_space(1))) unsigned int*)g,
      (__attribute__((address_space(3))) unsigned int*)l, 16, 0, 0);
}

// ---------------- Kernel 0: fp32 -> bf16 elementwise ------------------------
__global__ void cvt_f32_bf16(const float* __restrict__ src, u16* __restrict__ dst, int n4) {
  int i = blockIdx.x * 256 + threadIdx.x;
  if (i < n4) {
    float4 v = *reinterpret_cast<const float4*>(src + (size_t)i * 4);
    u16* d = dst + (size_t)i * 4;
    d[0] = f2bf(v.x); d[1] = f2bf(v.y); d[2] = f2bf(v.z); d[3] = f2bf(v.w);
  }
}

// ---------------- Kernel 1: weight transpose (fp32 in, bf16 out) ------------
__global__ void transpose_w_kernel(const float* __restrict__ Wq, const float* __restrict__ Wk,
                                   const float* __restrict__ Wv, u16* __restrict__ Wt) {
  __shared__ u16 tile[64][72];
  const int bid = blockIdx.x;
  const int et = bid & 15;
  const int h  = (bid >> 4) & 15;
  const int p  = bid >> 8;
  const float* W = (p == 0) ? Wq : ((p == 1) ? Wk : Wv);
  const int tid = threadIdx.x;
  for (int idx = tid; idx < 4096; idx += 256) {
    int i = idx >> 6, d = idx & 63;
    tile[d][i] = f2bf(W[(size_t)(h * 1024 + et * 64 + i) * 64 + d]);
  }
  __syncthreads();
  for (int idx = tid; idx < 4096; idx += 256) {
    int dd = idx >> 6, i = idx & 63;
    Wt[(size_t)(p * 1024 + h * 64 + dd) * 1024 + et * 64 + i] = tile[dd][i];
  }
}

// ---------------- Kernel 2/4: GEMM v12 (r23 state) ----------------------------
// 1 barrier per K-tile: load 16 frags, issue stage(t+2), 32 MFMA @setprio,
// vmcnt(6)+s_barrier.  Epilogues via LDS (conflict-free layouts).
template <int N, int MODE>
__global__ __launch_bounds__(512, 1)
void gemm_bt2(const u16* __restrict__ A, const u16* __restrict__ Bt,
              u16* __restrict__ O0, u16* __restrict__ O1, u16* __restrict__ O2,
              float* __restrict__ Of, const float* __restrict__ bias) {
  constexpr int K = 1024, BK = 64, NT = K / BK;
  constexpr int nbn = N / 128;
  constexpr int nwg = 32 * nbn;
  constexpr int ABYTES = 256 * BK * 2;             // 32KB
  constexpr int BUFBYTES = ABYTES + 128 * BK * 2;  // 48KB
  __shared__ char SM[3][BUFBYTES];                 // 144KB ring; reused by epilogue
  const int tid = threadIdx.x;
  const int lane = tid & 63;
  const int wid = tid >> 6;
  const int bid = (blockIdx.x & 7) * (nwg / 8) + (blockIdx.x >> 3);
  const int m0 = (bid / nbn) * 256, n0 = (bid % nbn) * 128;
  const int wm = (wid >> 1) * 64, wn = (wid & 1) * 64;
  const int fr = lane & 15;
  const int fgb = (lane >> 4) << 4;
  const int swz = (fr & 7) << 4;

  f32x4 acc[4][4];
#pragma unroll
  for (int i = 0; i < 4; ++i)
#pragma unroll
    for (int j = 0; j < 4; ++j) acc[i][j] = f32x4{0.f, 0.f, 0.f, 0.f};

  auto stage = [&](char* base, int k0) {
#pragma unroll
    for (int i = 0; i < 4; ++i) {
      int cbase = i * 512 + wid * 64;
      int chunk = cbase + lane;
      int row = chunk >> 3;
      int cole = ((chunk & 7) ^ (row & 7)) << 3;
      gload_lds16(A + (size_t)(m0 + row) * K + k0 + cole, base + cbase * 16);
    }
#pragma unroll
    for (int i = 0; i < 2; ++i) {
      int cbase = i * 512 + wid * 64;
      int chunk = cbase + lane;
      int row = chunk >> 3;
      int cole = ((chunk & 7) ^ (row & 7)) << 3;
      gload_lds16(Bt + (size_t)(n0 + row) * K + k0 + cole, base + ABYTES + cbase * 16);
    }
  };

  stage(&SM[0][0], 0);
  stage(&SM[1][0], BK);
  asm volatile("s_waitcnt vmcnt(6)" ::: "memory");
  __builtin_amdgcn_s_barrier();
  __builtin_amdgcn_sched_barrier(0);

  int bc = 0;
  for (int t = 0; t < NT; ++t) {
    char* Ab = &SM[0][0] + bc * BUFBYTES;
    char* Bb = Ab + ABYTES;
    bf16x8 af[2][4], bf[2][4];
#pragma unroll
    for (int kk = 0; kk < 2; ++kk) {
      const int colb = (kk * 64 + fgb) ^ swz;
#pragma unroll
      for (int mi = 0; mi < 4; ++mi)
        af[kk][mi] = *reinterpret_cast<const bf16x8*>(Ab + (wm + mi * 16 + fr) * 128 + colb);
#pragma unroll
      for (int ni = 0; ni < 4; ++ni)
        bf[kk][ni] = *reinterpret_cast<const bf16x8*>(Bb + (wn + ni * 16 + fr) * 128 + colb);
    }
    if (t + 2 < NT) {
      int bn = bc + 2; if (bn >= 3) bn -= 3;
      stage(&SM[0][0] + bn * BUFBYTES, (t + 2) * BK);
    }
    __builtin_amdgcn_s_setprio(1);
#pragma unroll
    for (int kk = 0; kk < 2; ++kk)
#pragma unroll
      for (int mi = 0; mi < 4; ++mi)
#pragma unroll
        for (int ni = 0; ni < 4; ++ni)
          acc[mi][ni] = __builtin_amdgcn_mfma_f32_16x16x32_bf16(af[kk][mi], bf[kk][ni], acc[mi][ni], 0, 0, 0);
    __builtin_amdgcn_s_setprio(0);
    __builtin_amdgcn_sched_barrier(0);
    if (t + 2 < NT)
      asm volatile("s_waitcnt vmcnt(6)" ::: "memory");
    else if (t + 1 < NT)
      asm volatile("s_waitcnt vmcnt(0)" ::: "memory");
    __builtin_amdgcn_s_barrier();
    __builtin_amdgcn_sched_barrier(0);
    ++bc; if (bc == 3) bc = 0;
  }

  const int rq = (lane >> 4) << 2;  // C/D: col = lane&15, row = (lane>>4)*4 + reg
  if constexpr (MODE == 0) {
    const int pr = n0 >> 10;             // uniform per block
    const int hh0 = (n0 >> 6) & 15;      // first of 2 heads in this block
    if (pr < 2) {
      u16* T = (u16*)&SM[0][0];
#pragma unroll
      for (int ni = 0; ni < 4; ++ni)
#pragma unroll
        for (int mi = 0; mi < 4; ++mi)
#pragma unroll
          for (int r = 0; r < 4; ++r)
            T[(wm + mi * 16 + rq + r) * 132 + wn + ni * 16 + fr] = f2bf(acc[mi][ni][r]);
      __builtin_amdgcn_s_barrier();
      u16* O = (pr == 0) ? O0 : O1;      // [B,H,1024,64]
#pragma unroll
      for (int k = 0; k < 8; ++k) {
        int ch = tid + k * 512;
        int c16 = ch & 7;
        int hhh = (ch >> 3) & 1;
        int m = ch >> 4;
        int mg = m0 + m;
        int b = mg >> 10, t = mg & 1023;
        const u16* src = &T[m * 132 + hhh * 64 + c16 * 8];
        uint2 lo = *(const uint2*)(src);
        uint2 hi = *(const uint2*)(src + 4);
        uint4 val = {lo.x, lo.y, hi.x, hi.y};
        *(uint4*)(O + ((size_t)(b * 16 + hh0 + hhh) * 1024 + t) * 64 + c16 * 8) = val;
      }
    } else {
      u16* T2 = (u16*)&SM[0][0];         // [n=128][m=260]
#pragma unroll
      for (int ni = 0; ni < 4; ++ni)
#pragma unroll
        for (int mi = 0; mi < 4; ++mi) {
          u16 tmp[4];
#pragma unroll
          for (int r = 0; r < 4; ++r) tmp[r] = f2bf(acc[mi][ni][r]);
          *(uint2*)&T2[(wn + ni * 16 + fr) * 260 + wm + mi * 16 + rq] = *(const uint2*)tmp;
        }
      __builtin_amdgcn_s_barrier();
      const int b = m0 >> 10, tb = m0 & 1023;
#pragma unroll
      for (int k = 0; k < 8; ++k) {
        int ch = tid + k * 512;
        int mc = ch & 31;
        int dd2 = ch >> 5;
        const u16* src = &T2[dd2 * 260 + mc * 8];
        uint2 lo = *(const uint2*)(src);
        uint2 hi = *(const uint2*)(src + 4);
        uint4 val = {lo.x, lo.y, hi.x, hi.y};
        int hhh = dd2 >> 6, dd = dd2 & 63;
        *(uint4*)(O2 + ((size_t)(b * 16 + hh0 + hhh) * 64 + dd) * 1024 + tb + mc * 8) = val;
      }
    }
  } else {
    float* Tf = (float*)&SM[0][0];       // 256*132*4 = 135KB
#pragma unroll
    for (int ni = 0; ni < 4; ++ni) {
      int n = n0 + wn + ni * 16 + fr;
      float bv = bias[n];
#pragma unroll
      for (int mi = 0; mi < 4; ++mi)
#pragma unroll
        for (int r = 0; r < 4; ++r)
          Tf[(wm + mi * 16 + rq + r) * 132 + wn + ni * 16 + fr] = acc[mi][ni][r] + bv;
    }
    __builtin_amdgcn_s_barrier();
#pragma unroll
    for (int k = 0; k < 16; ++k) {
      int ch = tid + k * 512;
      int mc = ch & 31;
      int m = ch >> 5;
      float4 val = *(const float4*)&Tf[m * 132 + mc * 4];
      *(float4*)(Of + (size_t)(m0 + m) * N + n0 + mc * 4) = val;
    }
  }
}

// ---------------- Kernel 3: causal flash attention (v15, r23 state) ----------
// (256,3)/48KB/1024-block design point, A/B-verified against: (256,2) [fewer
// waves], (256,4) [64-VGPR cap spill], 512-thr blocks [stiffer barriers +
// worse active-fraction].  Empirical VGPR caps (256-thr): (2)->128, (3)->85,
// (4)->64.
__global__ __launch_bounds__(256, 3)
void attn_fwd(const u16* __restrict__ Q, const u16* __restrict__ K,
              const u16* __restrict__ V, u16* __restrict__ O) {
  __shared__ u16 Ksm[2][4096];   // [buf][64 t-rows x 64 d-cols], col-swizzled
  __shared__ u16 Vsm[2][4096];   // [buf][64 d-rows x 64 t-cols], col-swizzled
  __shared__ u16 Pl[4][2048];    // per-wave P (2 frags x 16x64), XOR-swizzled
  const int tid = threadIdx.x, lane = tid & 63, w = tid >> 6;
  const int bid = blockIdx.x;
  const int bh = bid & 127;          // low bits -> XCD affinity per head
  const int c  = 7 - (bid >> 7);     // descending work order
  const int b = bh >> 4, h = bh & 15;
  const int q0w = c * 128 + w * 32;
  const int fr = lane & 15, fg = lane >> 4, fk = fg << 3;
  const int swz = (fr & 7) << 4;
  const int fgb = fg << 4;
  const u16* Qb = Q + (size_t)bh * 65536;
  const u16* Kb = K + (size_t)bh * 65536;
  const u16* Vb = V + (size_t)bh * 65536;
  char* Pw = (char*)&Pl[w][0];
  const float cst = 0.125f * 1.44269504088896f;   // hs^-0.5 * log2(e)
  const float THRraw = 8.0f / (0.125f * 1.44269504088896f);

  auto stage = [&](int buf, int st2) {
    const u16* Kt = Kb + st2 * 4096;
    const u16* Vt = Vb + st2 * 64;
#pragma unroll
    for (int i = 0; i < 2; ++i) {
      int cbase = i * 256 + w * 64;
      int chunk = cbase + lane;
      int row = chunk >> 3;
      int cole = ((chunk & 7) ^ (row & 7)) << 3;
      gload_lds16(Kt + row * 64 + cole, (char*)&Ksm[buf][0] + cbase * 16);
      gload_lds16(Vt + (size_t)row * 1024 + cole, (char*)&Vsm[buf][0] + cbase * 16);
    }
  };

  bf16x8 qf[2][2];
#pragma unroll
  for (int qm = 0; qm < 2; ++qm)
#pragma unroll
    for (int kk = 0; kk < 2; ++kk)
      qf[qm][kk] = *reinterpret_cast<const bf16x8*>(&Qb[(q0w + qm * 16 + fr) * 64 + kk * 32 + fk]);

  f32x4 o[2][4];
  float mraw[2][4], negm[2][4], lrow[2][4];
#pragma unroll
  for (int qm = 0; qm < 2; ++qm)
#pragma unroll
    for (int i = 0; i < 4; ++i) {
      o[qm][i] = f32x4{0.f, 0.f, 0.f, 0.f};
      mraw[qm][i] = -1e30f; negm[qm][i] = 1e30f * cst; lrow[qm][i] = 0.f;
    }

  const int stmaxb = 2 * c + 1;

  stage(0, 0);
  __syncthreads();
  int cur = 0;
  for (int st = 0; st <= stmaxb; ++st) {
    if (st < stmaxb) stage(cur ^ 1, st + 1);

    const bool active = (st * 64 <= q0w + 31);  // wave-uniform
    if (active) {
      f32x4 s[2][4];
#pragma unroll
      for (int qm = 0; qm < 2; ++qm)
#pragma unroll
        for (int i = 0; i < 4; ++i) s[qm][i] = f32x4{0.f, 0.f, 0.f, 0.f};
#pragma unroll
      for (int kk = 0; kk < 2; ++kk) {
        const int colb = (kk * 64 + fgb) ^ swz;
#pragma unroll
        for (int nf = 0; nf < 4; ++nf) {
          bf16x8 kf = *reinterpret_cast<const bf16x8*>(
              (const char*)&Ksm[cur][0] + (nf * 16 + fr) * 128 + colb);
          s[0][nf] = __builtin_amdgcn_mfma_f32_16x16x32_bf16(qf[0][kk], kf, s[0][nf], 0, 0, 0);
          s[1][nf] = __builtin_amdgcn_mfma_f32_16x16x32_bf16(qf[1][kk], kf, s[1][nf], 0, 0, 0);
        }
      }

#pragma unroll
      for (int qm = 0; qm < 2; ++qm) {
        const int qb = q0w + qm * 16;
        const bool need_mask = (st * 64 + 63 > qb);
        float sv[4][4];
#pragma unroll
        for (int nf = 0; nf < 4; ++nf)
#pragma unroll
          for (int r = 0; r < 4; ++r) {
            float xv = s[qm][nf][r];
            if (need_mask) {
              int sc = st * 64 + nf * 16 + fr;
              int qr = qb + fg * 4 + r;
              if (sc > qr) xv = -1e30f;
            }
            sv[nf][r] = xv;
          }
        float pmax[4];
#pragma unroll
        for (int r = 0; r < 4; ++r)
          pmax[r] = fmaxf(fmaxf(sv[0][r], sv[1][r]), fmaxf(sv[2][r], sv[3][r]));
        bool grew = (pmax[0] > mraw[qm][0] + THRraw) || (pmax[1] > mraw[qm][1] + THRraw) ||
                    (pmax[2] > mraw[qm][2] + THRraw) || (pmax[3] > mraw[qm][3] + THRraw);
        if (__any(grew)) {
#pragma unroll
          for (int r = 0; r < 4; ++r) {
            float m = pmax[r];
            m = fmaxf(m, __shfl_xor(m, 1));
            m = fmaxf(m, __shfl_xor(m, 2));
            m = fmaxf(m, __shfl_xor(m, 4));
            m = fmaxf(m, __shfl_xor(m, 8));
            float mnew = fmaxf(mraw[qm][r], m);
            float a = exp2f((mraw[qm][r] - mnew) * cst);
            lrow[qm][r] *= a;
            o[qm][0][r] *= a; o[qm][1][r] *= a; o[qm][2][r] *= a; o[qm][3][r] *= a;
            mraw[qm][r] = mnew;
            negm[qm][r] = -mnew * cst;
          }
        }
        char* Pq = Pw + qm * 2048;
#pragma unroll
        for (int r = 0; r < 4; ++r) {
          float sum = 0.f;
#pragma unroll
          for (int nf = 0; nf < 4; ++nf) {
            float pv = exp2f(fmaf(sv[nf][r], cst, negm[qm][r]));
            sum += pv;
            int mm = fg * 4 + r, nn = nf * 16 + fr;
            int byteoff = (mm * 128 + nn * 2) ^ ((mm & 7) << 4);
            *(u16*)(Pq + byteoff) = f2bf_t(pv);   // truncating pack (P only)
          }
          lrow[qm][r] += sum;
        }
      }

#pragma unroll
      for (int kk = 0; kk < 2; ++kk) {
        int rb = (fr * 128 + kk * 64 + fg * 16) ^ ((fr & 7) << 4);
        bf16x8 pa0 = *reinterpret_cast<const bf16x8*>(Pw + rb);
        bf16x8 pa1 = *reinterpret_cast<const bf16x8*>(Pw + 2048 + rb);
        const int colb = (kk * 64 + fgb) ^ swz;
#pragma unroll
        for (int df = 0; df < 4; ++df) {
          bf16x8 vfv = *reinterpret_cast<const bf16x8*>(
              (const char*)&Vsm[cur][0] + (df * 16 + fr) * 128 + colb);
          o[0][df] = __builtin_amdgcn_mfma_f32_16x16x32_bf16(pa0, vfv, o[0][df], 0, 0, 0);
          o[1][df] = __builtin_amdgcn_mfma_f32_16x16x32_bf16(pa1, vfv, o[1][df], 0, 0, 0);
        }
      }
    }

    __syncthreads();
    cur ^= 1;
  }

#pragma unroll
  for (int qm = 0; qm < 2; ++qm)
#pragma unroll
    for (int r = 0; r < 4; ++r) {
      float sum = lrow[qm][r];
      sum += __shfl_xor(sum, 1);
      sum += __shfl_xor(sum, 2);
      sum += __shfl_xor(sum, 4);
      sum += __shfl_xor(sum, 8);
      float inv = 1.0f / sum;
      int t = q0w + qm * 16 + fg * 4 + r;
      size_t base = ((size_t)b * 1024 + t) * 1024 + h * 64;
#pragma unroll
      for (int df = 0; df < 4; ++df) O[base + df * 16 + fr] = f2bf(o[qm][df][r] * inv);
    }
}

// ---------------- launcher ---------------------------------------------------
extern "C" void kernel_launch(void* const* d_in, const int* in_sizes, int n_in,
                              void* d_out, int out_size, void* d_ws, size_t ws_size,
                              hipStream_t stream) {
  (void)in_sizes; (void)n_in; (void)out_size; (void)ws_size;
  const float* x  = (const float*)d_in[0];
  const float* Wq = (const float*)d_in[1];
  const float* Wk = (const float*)d_in[2];
  const float* Wv = (const float*)d_in[3];
  const float* Wp = (const float*)d_in[4];
  const float* bp = (const float*)d_in[5];
  float* out = (float*)d_out;

  char* ws = (char*)d_ws;
  u16* xb  = (u16*)(ws);              // 16MB, reused as Ob after attn input dead
  u16* Ob  = (u16*)(ws);
  u16* Wt  = (u16*)(ws + 16777216);   // 6MB, reused as Wpb
  u16* Wpb = (u16*)(ws + 16777216);
  u16* Qb  = (u16*)(ws + 23068672);   // 16 MB: [B,H,1024,64]
  u16* Kb  = (u16*)(ws + 39845888);   // 16 MB
  u16* Vt  = (u16*)(ws + 56623104);   // 16 MB: [B,H,64,1024]

  cvt_f32_bf16<<<8192, 256, 0, stream>>>(x, xb, 2097152);
  transpose_w_kernel<<<768, 256, 0, stream>>>(Wq, Wk, Wv, Wt);
  gemm_bt2<3072, 0><<<768, 512, 0, stream>>>(xb, Wt, Qb, Kb, Vt, nullptr, nullptr);
  cvt_f32_bf16<<<1024, 256, 0, stream>>>(Wp, Wpb, 262144);
  attn_fwd<<<1024, 256, 0, stream>>>(Qb, Kb, Vt, Ob);
  gemm_bt2<1024, 1><<<256, 512, 0, stream>>>(Ob, Wpb, nullptr, nullptr, nullptr, out, bp);
}